// Round 9
// baseline (749.114 us; speedup 1.0000x reference)
//
#include <hip/hip_runtime.h>
#include <cstdint>

// SpikingCNN: B=8192, D=784, H=128, O=10, T=20, beta=0.9, thr=1.0
// Round-9: JAX >= 0.4.30 defaults jax_threefry_partitionable=True. Spikegen
// therefore uses the PER-ELEMENT PRF: for flat index n (C-order over
// (T,B,D), n < 2^32 so hi=0):
//   (x0,x1) = threefry2x32(key=(0,42), counter=(0, n));  bits = x0 ^ x1
//   u = bitcast((bits>>9)|0x3f800000) - 1.0f;  spike = (u < p)
// (previous rounds implemented the legacy split-halves stream -> independent
// realization -> the 8x bit-identical absmax=2-spike-counts plateau).
// A : fused spikegen + GEMM1, fp32 single ascending-k FMA chain (products
//     {0,1}*w exact). One t + 128 batch rows per block.
// B1: LIF1 recurrence per row (4 lanes/row), packs spike bitmasks -> ws.
// B2: layer-2 ascending-h add chain + LIF2 -> out.

#define T_STEPS 20
#define B_SZ   8192
#define D_SZ   784
#define H_SZ   128
#define O_SZ   10
#define CUR1_BYTES (20u * 8192u * 128u * 4u)   // 83,886,080

__device__ __forceinline__ uint32_t rotl32(uint32_t x, uint32_t d) {
  return (x << d) | (x >> (32u - d));
}

// JAX threefry2x32, key = (0, 42) from jax.random.key(42).
__device__ __forceinline__ void threefry_0_42(uint32_t c0, uint32_t c1,
                                              uint32_t& o0, uint32_t& o1) {
  const uint32_t ks0 = 0u;
  const uint32_t ks1 = 42u;
  const uint32_t ks2 = 0u ^ 42u ^ 0x1BD11BDAu;
  uint32_t x0 = c0 + ks0;
  uint32_t x1 = c1 + ks1;
#define TF_R(rot) { x0 += x1; x1 = rotl32(x1, rot); x1 ^= x0; }
  TF_R(13u) TF_R(15u) TF_R(26u) TF_R(6u)
  x0 += ks1; x1 += ks2 + 1u;
  TF_R(17u) TF_R(29u) TF_R(16u) TF_R(24u)
  x0 += ks2; x1 += ks0 + 2u;
  TF_R(13u) TF_R(15u) TF_R(26u) TF_R(6u)
  x0 += ks0; x1 += ks1 + 3u;
  TF_R(17u) TF_R(29u) TF_R(16u) TF_R(24u)
  x0 += ks1; x1 += ks2 + 4u;
  TF_R(13u) TF_R(15u) TF_R(26u) TF_R(6u)
  x0 += ks2; x1 += ks0 + 5u;
#undef TF_R
  o0 = x0; o1 = x1;
}

// uniform in [0,1): bitcast((bits>>9)|0x3f800000) - 1.0  (JAX _uniform, f32)
__device__ __forceinline__ float tf_uniform(uint32_t bits) {
  return __uint_as_float((bits >> 9) | 0x3f800000u) - 1.0f;
}

// ---------------------------------------------------------------------------
// Kernel A: grid = 20 (t) * 64 (b-tiles of 128). Block 256 threads.
// C-tile: 128 batch rows x 128 h. Partitionable-threefry spikegen fused.
// ---------------------------------------------------------------------------
__global__ __launch_bounds__(256) void spike_gemm1(
    const float* __restrict__ x, const float* __restrict__ w1,
    const float* __restrict__ b1, float* __restrict__ cur1) {
  __shared__ __align__(16) float sW[16][132];  // sW[dd][h]
  __shared__ __align__(16) float sS[16][132];  // sS[dd][bb], bb = local row

  const int tid = threadIdx.x;
  const int t  = blockIdx.x >> 6;            // 0..19
  const int b0 = (blockIdx.x & 63) << 7;     // batch tile start (128 rows)

  float acc[8][8];
#pragma unroll
  for (int i = 0; i < 8; ++i)
#pragma unroll
    for (int j = 0; j < 8; ++j) acc[i][j] = 0.0f;

  const int r0 = (tid >> 4) << 3;  // local row group 0..120
  const int h0 = (tid & 15) << 3;  // h group 0..120

  const uint32_t tbase = (uint32_t)t * (uint32_t)(B_SZ * D_SZ);

  for (int k0 = 0; k0 < D_SZ; k0 += 16) {
    __syncthreads();
    // stage W1 chunk: 2048 elems
#pragma unroll
    for (int i = 0; i < 8; ++i) {
      int idx = tid + (i << 8);
      int h  = idx >> 4;
      int dd = idx & 15;
      sW[dd][h] = w1[h * D_SZ + k0 + dd];
    }
    // spikegen: 128 rows x 16 d = 2048 elems, one threefry each
#pragma unroll
    for (int pass = 0; pass < 8; ++pass) {
      int idx = tid + (pass << 8);   // 0..2047
      int bb = idx >> 4;
      int dd = idx & 15;
      int b  = b0 + bb;
      int bd = b * D_SZ + k0 + dd;
      float pr = x[bd];
      uint32_t n = tbase + (uint32_t)bd;   // flat index, hi32 == 0
      uint32_t o0, o1;
      threefry_0_42(0u, n, o0, o1);
      sS[dd][bb] = (tf_uniform(o0 ^ o1) < pr) ? 1.0f : 0.0f;
    }
    __syncthreads();
#pragma unroll
    for (int dd = 0; dd < 16; ++dd) {
      float4 a0 = *(const float4*)&sS[dd][r0];
      float4 a1 = *(const float4*)&sS[dd][r0 + 4];
      float4 w0 = *(const float4*)&sW[dd][h0];
      float4 w4 = *(const float4*)&sW[dd][h0 + 4];
      float av[8] = {a0.x, a0.y, a0.z, a0.w, a1.x, a1.y, a1.z, a1.w};
      float wv[8] = {w0.x, w0.y, w0.z, w0.w, w4.x, w4.y, w4.z, w4.w};
#pragma unroll
      for (int i = 0; i < 8; ++i)
#pragma unroll
        for (int j = 0; j < 8; ++j)
          acc[i][j] = __builtin_fmaf(av[i], wv[j], acc[i][j]);
    }
  }

  float bias[8];
#pragma unroll
  for (int j = 0; j < 8; ++j) bias[j] = b1[h0 + j];
#pragma unroll
  for (int i = 0; i < 8; ++i) {
    int b = b0 + r0 + i;
    size_t off = ((size_t)t * B_SZ + (size_t)b) * H_SZ + h0;
    float4 v0, v1;
    v0.x = acc[i][0] + bias[0]; v0.y = acc[i][1] + bias[1];
    v0.z = acc[i][2] + bias[2]; v0.w = acc[i][3] + bias[3];
    v1.x = acc[i][4] + bias[4]; v1.y = acc[i][5] + bias[5];
    v1.z = acc[i][6] + bias[6]; v1.w = acc[i][7] + bias[7];
    *(float4*)&cur1[off]     = v0;
    *(float4*)&cur1[off + 4] = v1;
  }
}

// ---------------------------------------------------------------------------
// Kernel B1: LIF1 recurrence, 4 lanes/row; lane p owns h = j*16 + p*4 + q
// (local i = j*4+q). Packs per-(t,row) 128-bit spike mask (bit index == h)
// into 4 uint32 words; lane p stores word p -> fully coalesced.
// ---------------------------------------------------------------------------
__global__ __launch_bounds__(256) void lif1_spikes(
    const float* __restrict__ cur1, uint32_t* __restrict__ masks) {
#pragma clang fp contract(off)
  const int g   = blockIdx.x * 256 + threadIdx.x;
  const int row = g >> 2;
  const int p   = g & 3;

  float mem1[32];
#pragma unroll
  for (int i = 0; i < 32; ++i) mem1[i] = 0.0f;

  const float4* base = (const float4*)cur1;

  for (int t = 0; t < T_STEPS; ++t) {
    size_t rb = ((size_t)t * B_SZ + (size_t)row) * (H_SZ / 4) + p;
    float4 c[8];
#pragma unroll
    for (int j = 0; j < 8; ++j) c[j] = base[rb + (size_t)j * 4];

    uint32_t spkbits = 0u;   // bit i = spike of local mem index i
#pragma unroll
    for (int j = 0; j < 8; ++j) {
      float cv[4] = {c[j].x, c[j].y, c[j].z, c[j].w};
#pragma unroll
      for (int q = 0; q < 4; ++q) {
        int i = j * 4 + q;
        float m = mem1[i];
        float reset = (m > 1.0f) ? 1.0f : 0.0f;
        m = 0.9f * m;     // separate rounded ops (contract off) to match ref
        m = m + cv[q];
        m = m - reset;
        mem1[i] = m;
        spkbits |= (m > 1.0f) ? (1u << i) : 0u;
      }
    }
    // local i = 8w + 4*j2 + q maps to mask word w, bit 16*j2 + 4*p + q
    uint32_t myword = 0u;
#pragma unroll
    for (int w = 0; w < 4; ++w) {
      uint32_t part = (((spkbits >> (8 * w)) & 0xFu) << (4 * p)) |
                      (((spkbits >> (8 * w + 4)) & 0xFu) << (16 + 4 * p));
      part |= __shfl_xor(part, 1);
      part |= __shfl_xor(part, 2);
      if (w == p) myword = part;
    }
    masks[(size_t)t * (B_SZ * 4) + (size_t)g] = myword;  // g == row*4+p
  }
}

// ---------------------------------------------------------------------------
// Kernel B2: per (row, o) lane. cur2 = strict ascending-h chain of
// (spike? w2[o][h] : 0) adds (exact products), + bias, then LIF2 + count.
// Block = 320 threads (5 waves): o = (blockIdx&1)*5 + wave, rows = 64/lane.
// ---------------------------------------------------------------------------
__global__ __launch_bounds__(320) void lif2_seq(
    const float* __restrict__ w2, const float* __restrict__ b2,
    const uint32_t* __restrict__ masks, float* __restrict__ out) {
#pragma clang fp contract(off)
  __shared__ __align__(16) float sW2[O_SZ][H_SZ];
  const int tid = threadIdx.x;
  for (int i = tid; i < O_SZ * H_SZ; i += 320)
    sW2[i >> 7][i & 127] = w2[i];
  __syncthreads();

  const int wave = tid >> 6;                 // 0..4
  const int lane = tid & 63;
  const int row  = ((blockIdx.x >> 1) << 6) + lane;
  const int o    = (blockIdx.x & 1) * 5 + wave;
  const float bias = b2[o];

  float mem2 = 0.0f;
  int cnt = 0;
  const uint4* mbase = (const uint4*)masks;  // [20][8192] x uint4

  for (int t = 0; t < T_STEPS; ++t) {
    uint4 m = mbase[(size_t)t * B_SZ + row];
    uint32_t mw[4] = {m.x, m.y, m.z, m.w};
    float acc = 0.0f;
#pragma unroll
    for (int w = 0; w < 4; ++w) {
#pragma unroll
      for (int hc = 0; hc < 8; ++hc) {
        float4 wv = *(const float4*)&sW2[o][w * 32 + hc * 4];
        float vv[4] = {wv.x, wv.y, wv.z, wv.w};
#pragma unroll
        for (int bb = 0; bb < 4; ++bb) {
          float val = ((mw[w] >> (hc * 4 + bb)) & 1u) ? vv[bb] : 0.0f;
          acc = acc + val;   // strict ascending-h chain
        }
      }
    }
    float c2 = acc + bias;
    float reset = (mem2 > 1.0f) ? 1.0f : 0.0f;
    mem2 = 0.9f * mem2;
    mem2 = mem2 + c2;
    mem2 = mem2 - reset;
    cnt += (mem2 > 1.0f) ? 1 : 0;
  }
  out[row * O_SZ + o] = (float)cnt / 20.0f;
}

extern "C" void kernel_launch(void* const* d_in, const int* in_sizes, int n_in,
                              void* d_out, int out_size, void* d_ws, size_t ws_size,
                              hipStream_t stream) {
  const float* x   = (const float*)d_in[0];  // [8192,784]
  const float* w1  = (const float*)d_in[1];  // [128,784]
  const float* b1  = (const float*)d_in[2];  // [128]
  const float* w2  = (const float*)d_in[3];  // [10,128]
  const float* b2  = (const float*)d_in[4];  // [10]
  float* out  = (float*)d_out;               // [8192,10]
  float* cur1 = (float*)d_ws;                // [20,8192,128] fp32 = 84 MB
  uint32_t* masks = (uint32_t*)((char*)d_ws + CUR1_BYTES);  // [20][8192][4] u32

  spike_gemm1<<<dim3(1280), dim3(256), 0, stream>>>(x, w1, b1, cur1);
  lif1_spikes<<<dim3(128), dim3(256), 0, stream>>>(cur1, masks);
  lif2_seq<<<dim3(256), dim3(320), 0, stream>>>(w2, b2, masks, out);
}

// Round 10
// 483.066 us; speedup vs baseline: 1.5507x; 1.5507x over previous
//
#include <hip/hip_runtime.h>
#include <cstdint>

// SpikingCNN: B=8192, D=784, H=128, O=10, T=20, beta=0.9, thr=1.0
// R10: move GEMM1 from fp32 VALU (209us floor, was 727us total) to MFMA via
// EXACT 3-way bf16 split of w1 (w = hi+mid+lo, Dekker: 24 mant bits = 3x8;
// spikes {0,1} exact in bf16 -> all products exact; fp32 accumulate inside
// mfma). Ulp-class reordering proven safe by r9 (single f32 chain matched
// CPU-BLAS-ordered ref with 0/21M decision flips).
// W : pre-kernel splits w1 -> 3 bf16 planes [3][128][800] (k-padded w/ 0).
// A : fused partitionable-threefry spikegen + triple-plane bf16 MFMA GEMM.
//     RNG (verified r9): (x0,x1)=threefry2x32((0,42),(0,n)), n=t*B*D+b*D+d,
//     bits=x0^x1, u=bitcast((bits>>9)|0x3f800000)-1, spike=(u<p).
// B1: LIF1 recurrence per row (4 lanes/row), packs spike bitmasks -> ws.
// B2: layer-2 ascending-h add chain + LIF2 -> out.

#define T_STEPS 20
#define B_SZ   8192
#define D_SZ   784
#define H_SZ   128
#define O_SZ   10
#define CUR1_BYTES  83886080u   // 20*8192*128*4
#define MASKS_BYTES 655360u     // 20*8192*4*4
#define WPLANE_OFF  (CUR1_BYTES + MASKS_BYTES)   // 84541440, 16B aligned

typedef __attribute__((ext_vector_type(8))) short short8;
typedef __attribute__((ext_vector_type(4))) float f32x4;
typedef unsigned short ushort_t;

__device__ __forceinline__ uint32_t rotl32(uint32_t x, uint32_t d) {
  return (x << d) | (x >> (32u - d));
}

// JAX threefry2x32, key = (0, 42) from jax.random.key(42).
__device__ __forceinline__ void threefry_0_42(uint32_t c0, uint32_t c1,
                                              uint32_t& o0, uint32_t& o1) {
  const uint32_t ks0 = 0u;
  const uint32_t ks1 = 42u;
  const uint32_t ks2 = 0u ^ 42u ^ 0x1BD11BDAu;
  uint32_t x0 = c0 + ks0;
  uint32_t x1 = c1 + ks1;
#define TF_R(rot) { x0 += x1; x1 = rotl32(x1, rot); x1 ^= x0; }
  TF_R(13u) TF_R(15u) TF_R(26u) TF_R(6u)
  x0 += ks1; x1 += ks2 + 1u;
  TF_R(17u) TF_R(29u) TF_R(16u) TF_R(24u)
  x0 += ks2; x1 += ks0 + 2u;
  TF_R(13u) TF_R(15u) TF_R(26u) TF_R(6u)
  x0 += ks0; x1 += ks1 + 3u;
  TF_R(17u) TF_R(29u) TF_R(16u) TF_R(24u)
  x0 += ks1; x1 += ks2 + 4u;
  TF_R(13u) TF_R(15u) TF_R(26u) TF_R(6u)
  x0 += ks2; x1 += ks0 + 5u;
#undef TF_R
  o0 = x0; o1 = x1;
}

__device__ __forceinline__ float tf_uniform(uint32_t bits) {
  return __uint_as_float((bits >> 9) | 0x3f800000u) - 1.0f;
}

// RNE round of f32 to bf16 (upper 16 bits), returned as uint16 payload.
__device__ __forceinline__ uint32_t rne_bf16_bits(float f) {
  uint32_t u = __float_as_uint(f);
  return (u + 0x7fffu + ((u >> 16) & 1u)) & 0xffff0000u;
}

// ---------------------------------------------------------------------------
// Pre-kernel: split w1 f32 [128][784] into 3 exact bf16 planes [128][800]
// (k 784..799 zero-padded). grid = 128 (h), block = 256.
// ---------------------------------------------------------------------------
__global__ __launch_bounds__(256) void split_w1(
    const float* __restrict__ w1, ushort_t* __restrict__ wp) {
  const int h = blockIdx.x;
  for (int k = threadIdx.x; k < 800; k += 256) {
    float w = (k < D_SZ) ? w1[h * D_SZ + k] : 0.0f;
    uint32_t hb = rne_bf16_bits(w);
    float hi = __uint_as_float(hb);
    float r1 = w - hi;                      // exact (Sterbenz)
    uint32_t mb = rne_bf16_bits(r1);
    float mid = __uint_as_float(mb);
    float lo = r1 - mid;                    // exact, <=8 significant bits
    uint32_t lb = __float_as_uint(lo);      // low 16 mantissa bits are 0
    wp[0 * 102400 + h * 800 + k] = (ushort_t)(hb >> 16);
    wp[1 * 102400 + h * 800 + k] = (ushort_t)(mb >> 16);
    wp[2 * 102400 + h * 800 + k] = (ushort_t)(lb >> 16);
  }
}

// ---------------------------------------------------------------------------
// Kernel A: fused spikegen + MFMA GEMM. grid = 1280 (163840 flat rows / 128),
// block = 256 (4 waves, 2x2 quadrants of the 128x128 C-tile).
// K-loop: 25 chunks of 32 (K padded to 800). Per wave/chunk: 48 mfma
// (4m x 4n x 3 planes) + 16 ds_read_b128.
// ---------------------------------------------------------------------------
__global__ __launch_bounds__(256) void spike_gemm1_mfma(
    const float* __restrict__ x, const ushort_t* __restrict__ wp,
    const float* __restrict__ b1, float* __restrict__ cur1) {
  __shared__ __align__(16) ushort_t sS[128 * 40];      // spikes [row][k], pad->stride 40
  __shared__ __align__(16) ushort_t sW[3][128 * 40];   // weight planes [h][k]

  const int tid  = threadIdx.x;
  const int row0 = blockIdx.x << 7;          // flat row = t*8192 + b
  const int wave = tid >> 6, lane = tid & 63;
  const int wr0  = (wave >> 1) << 6;         // wave row offset (0/64)
  const int wc0  = (wave & 1) << 6;          // wave col offset (0/64)
  const int lm   = lane & 15, quad = lane >> 4;

  f32x4 acc[4][4];
#pragma unroll
  for (int m = 0; m < 4; ++m)
#pragma unroll
    for (int nn = 0; nn < 4; ++nn) acc[m][nn] = (f32x4){0.f, 0.f, 0.f, 0.f};

  // spikegen mapping: waves 0-1 -> k-half 0, waves 2-3 -> k-half 1 (wave-uniform)
  const int srow  = tid & 127;
  const int shalf = tid >> 7;
  const uint32_t nbase = (uint32_t)(row0 + srow) * 784u;
  const float* xrow = x + (size_t)((uint32_t)(row0 + srow) & 8191u) * D_SZ;

  for (int ko = 0; ko < 25; ++ko) {
    const int k0 = ko << 5;
    __syncthreads();
    // ---- stage W planes: 3*128*32 bf16 = 1536 x 16B units, 6 per thread ----
#pragma unroll
    for (int i = 0; i < 6; ++i) {
      int u = tid + (i << 8);
      int p = u >> 9;
      int v = u & 511;
      int h = v >> 2, kp = v & 3;
      const short8 g = *(const short8*)&wp[p * 102400 + h * 800 + k0 + kp * 8];
      *(short8*)&sW[p][h * 40 + kp * 8] = g;
    }
    // ---- spikes: 16 per thread (one row-half of the 32-k chunk) ----
    {
      const int kbase = k0 + shalf * 16;
      short8 s0 = (short8)0, s1 = (short8)0;
      if (kbase < D_SZ) {                     // wave-uniform branch
#pragma unroll
        for (int q = 0; q < 4; ++q) {
          float4 xv = *(const float4*)&xrow[kbase + q * 4];
          float pr[4] = {xv.x, xv.y, xv.z, xv.w};
#pragma unroll
          for (int jj = 0; jj < 4; ++jj) {
            int j = q * 4 + jj;
            uint32_t n = nbase + (uint32_t)(kbase + j);
            uint32_t o0, o1;
            threefry_0_42(0u, n, o0, o1);
            short sv = (tf_uniform(o0 ^ o1) < pr[jj]) ? (short)0x3F80 : (short)0;
            if (j < 8) s0[j] = sv; else s1[j - 8] = sv;
          }
        }
      }
      *(short8*)&sS[srow * 40 + shalf * 16]     = s0;
      *(short8*)&sS[srow * 40 + shalf * 16 + 8] = s1;
    }
    __syncthreads();
    // ---- MFMA: A = spikes (m = lane&15 rows), B = weight plane (n = h) ----
    short8 a[4];
#pragma unroll
    for (int m = 0; m < 4; ++m)
      a[m] = *(const short8*)&sS[(wr0 + m * 16 + lm) * 40 + quad * 8];
#pragma unroll
    for (int p = 0; p < 3; ++p) {
#pragma unroll
      for (int nn = 0; nn < 4; ++nn) {
        short8 bfr = *(const short8*)&sW[p][(wc0 + nn * 16 + lm) * 40 + quad * 8];
#pragma unroll
        for (int m = 0; m < 4; ++m)
          acc[m][nn] = __builtin_amdgcn_mfma_f32_16x16x32_bf16(
              a[m], bfr, acc[m][nn], 0, 0, 0);
      }
    }
  }

  // ---- epilogue: C/D layout col=lane&15, row=quad*4+reg; + bias, store ----
#pragma unroll
  for (int nn = 0; nn < 4; ++nn) {
    int col = wc0 + nn * 16 + lm;
    float bias = b1[col];
#pragma unroll
    for (int m = 0; m < 4; ++m) {
#pragma unroll
      for (int r = 0; r < 4; ++r) {
        int grow = row0 + wr0 + m * 16 + quad * 4 + r;
        cur1[(size_t)grow * H_SZ + col] = acc[m][nn][r] + bias;
      }
    }
  }
}

// ---------------------------------------------------------------------------
// Kernel B1: LIF1 recurrence, 4 lanes/row; packs per-(t,row) 128-bit spike
// mask into 4 u32 words (bit index == h). Unchanged from r9 (verified).
// ---------------------------------------------------------------------------
__global__ __launch_bounds__(256) void lif1_spikes(
    const float* __restrict__ cur1, uint32_t* __restrict__ masks) {
#pragma clang fp contract(off)
  const int g   = blockIdx.x * 256 + threadIdx.x;
  const int row = g >> 2;
  const int p   = g & 3;

  float mem1[32];
#pragma unroll
  for (int i = 0; i < 32; ++i) mem1[i] = 0.0f;

  const float4* base = (const float4*)cur1;

  for (int t = 0; t < T_STEPS; ++t) {
    size_t rb = ((size_t)t * B_SZ + (size_t)row) * (H_SZ / 4) + p;
    float4 c[8];
#pragma unroll
    for (int j = 0; j < 8; ++j) c[j] = base[rb + (size_t)j * 4];

    uint32_t spkbits = 0u;
#pragma unroll
    for (int j = 0; j < 8; ++j) {
      float cv[4] = {c[j].x, c[j].y, c[j].z, c[j].w};
#pragma unroll
      for (int q = 0; q < 4; ++q) {
        int i = j * 4 + q;
        float m = mem1[i];
        float reset = (m > 1.0f) ? 1.0f : 0.0f;
        m = 0.9f * m;
        m = m + cv[q];
        m = m - reset;
        mem1[i] = m;
        spkbits |= (m > 1.0f) ? (1u << i) : 0u;
      }
    }
    uint32_t myword = 0u;
#pragma unroll
    for (int w = 0; w < 4; ++w) {
      uint32_t part = (((spkbits >> (8 * w)) & 0xFu) << (4 * p)) |
                      (((spkbits >> (8 * w + 4)) & 0xFu) << (16 + 4 * p));
      part |= __shfl_xor(part, 1);
      part |= __shfl_xor(part, 2);
      if (w == p) myword = part;
    }
    masks[(size_t)t * (B_SZ * 4) + (size_t)g] = myword;
  }
}

// ---------------------------------------------------------------------------
// Kernel B2: layer-2 ascending-h add chain + LIF2. Unchanged from r9.
// ---------------------------------------------------------------------------
__global__ __launch_bounds__(320) void lif2_seq(
    const float* __restrict__ w2, const float* __restrict__ b2,
    const uint32_t* __restrict__ masks, float* __restrict__ out) {
#pragma clang fp contract(off)
  __shared__ __align__(16) float sW2[O_SZ][H_SZ];
  const int tid = threadIdx.x;
  for (int i = tid; i < O_SZ * H_SZ; i += 320)
    sW2[i >> 7][i & 127] = w2[i];
  __syncthreads();

  const int wave = tid >> 6;
  const int lane = tid & 63;
  const int row  = ((blockIdx.x >> 1) << 6) + lane;
  const int o    = (blockIdx.x & 1) * 5 + wave;
  const float bias = b2[o];

  float mem2 = 0.0f;
  int cnt = 0;
  const uint4* mbase = (const uint4*)masks;

  for (int t = 0; t < T_STEPS; ++t) {
    uint4 m = mbase[(size_t)t * B_SZ + row];
    uint32_t mw[4] = {m.x, m.y, m.z, m.w};
    float acc = 0.0f;
#pragma unroll
    for (int w = 0; w < 4; ++w) {
#pragma unroll
      for (int hc = 0; hc < 8; ++hc) {
        float4 wv = *(const float4*)&sW2[o][w * 32 + hc * 4];
        float vv[4] = {wv.x, wv.y, wv.z, wv.w};
#pragma unroll
        for (int bb = 0; bb < 4; ++bb) {
          float val = ((mw[w] >> (hc * 4 + bb)) & 1u) ? vv[bb] : 0.0f;
          acc = acc + val;
        }
      }
    }
    float c2 = acc + bias;
    float reset = (mem2 > 1.0f) ? 1.0f : 0.0f;
    mem2 = 0.9f * mem2;
    mem2 = mem2 + c2;
    mem2 = mem2 - reset;
    cnt += (mem2 > 1.0f) ? 1 : 0;
  }
  out[row * O_SZ + o] = (float)cnt / 20.0f;
}

extern "C" void kernel_launch(void* const* d_in, const int* in_sizes, int n_in,
                              void* d_out, int out_size, void* d_ws, size_t ws_size,
                              hipStream_t stream) {
  const float* x   = (const float*)d_in[0];  // [8192,784]
  const float* w1  = (const float*)d_in[1];  // [128,784]
  const float* b1  = (const float*)d_in[2];  // [128]
  const float* w2  = (const float*)d_in[3];  // [10,128]
  const float* b2  = (const float*)d_in[4];  // [10]
  float* out  = (float*)d_out;               // [8192,10]
  float* cur1 = (float*)d_ws;                                  // 84 MB
  uint32_t* masks = (uint32_t*)((char*)d_ws + CUR1_BYTES);     // 0.66 MB
  ushort_t* wp    = (ushort_t*)((char*)d_ws + WPLANE_OFF);     // 3*128*800 bf16

  split_w1<<<dim3(128), dim3(256), 0, stream>>>(w1, wp);
  spike_gemm1_mfma<<<dim3(1280), dim3(256), 0, stream>>>(x, wp, b1, cur1);
  lif1_spikes<<<dim3(128), dim3(256), 0, stream>>>(cur1, masks);
  lif2_seq<<<dim3(256), dim3(320), 0, stream>>>(w2, b2, masks, out);
}